// Round 2
// baseline (5467.938 us; speedup 1.0000x reference)
//
#include <hip/hip_runtime.h>
#include <cstdint>
#include <cstddef>

namespace {
constexpr int LB   = 4096;           // rows per batch element
constexpr int CS   = 32;
constexpr int NCH  = 128;            // LB / CS
constexpr int GINC = 1792;
constexpr int GHC  = 1024;
}

__device__ __forceinline__ float dot4(float4 a, float4 b) {
  return a.x*b.x + a.y*b.y + a.z*b.z + a.w*b.w;
}

// ---------------------------------------------------------------------------
// Tiled fp32 GEMM:  C[M,N] = A[M,K] @ W[N,K]^T
// 128x128 tile, BK=16, 256 threads, 8x8 per-thread micro tile.
// ---------------------------------------------------------------------------
__global__ __launch_bounds__(256)
void gemm_bt(const float* __restrict__ A, const float* __restrict__ W,
             float* __restrict__ C, int M, int N, int K) {
  __shared__ float As[16][128];
  __shared__ float Bs[16][128];
  const int tid = threadIdx.x;
  const int bn = blockIdx.x * 128;
  const int bm = blockIdx.y * 128;
  const int tx = tid & 15, ty = tid >> 4;
  const int lr = tid >> 1, lk = (tid & 1) * 8;

  float acc[8][8];
  #pragma unroll
  for (int i = 0; i < 8; ++i)
    #pragma unroll
    for (int j = 0; j < 8; ++j) acc[i][j] = 0.f;

  const float* Ap = A + (size_t)(bm + lr) * K + lk;
  const float* Wp = W + (size_t)(bn + lr) * K + lk;

  for (int k0 = 0; k0 < K; k0 += 16) {
    float4 a0 = *(const float4*)(Ap + k0);
    float4 a1 = *(const float4*)(Ap + k0 + 4);
    float4 b0 = *(const float4*)(Wp + k0);
    float4 b1 = *(const float4*)(Wp + k0 + 4);
    __syncthreads();
    As[lk+0][lr]=a0.x; As[lk+1][lr]=a0.y; As[lk+2][lr]=a0.z; As[lk+3][lr]=a0.w;
    As[lk+4][lr]=a1.x; As[lk+5][lr]=a1.y; As[lk+6][lr]=a1.z; As[lk+7][lr]=a1.w;
    Bs[lk+0][lr]=b0.x; Bs[lk+1][lr]=b0.y; Bs[lk+2][lr]=b0.z; Bs[lk+3][lr]=b0.w;
    Bs[lk+4][lr]=b1.x; Bs[lk+5][lr]=b1.y; Bs[lk+6][lr]=b1.z; Bs[lk+7][lr]=b1.w;
    __syncthreads();
    #pragma unroll
    for (int kk = 0; kk < 16; ++kk) {
      float av[8], bv[8];
      *(float4*)(av)   = *(const float4*)&As[kk][ty*8];
      *(float4*)(av+4) = *(const float4*)&As[kk][ty*8+4];
      *(float4*)(bv)   = *(const float4*)&Bs[kk][tx*8];
      *(float4*)(bv+4) = *(const float4*)&Bs[kk][tx*8+4];
      #pragma unroll
      for (int i = 0; i < 8; ++i)
        #pragma unroll
        for (int j = 0; j < 8; ++j) acc[i][j] += av[i]*bv[j];
    }
  }

  #pragma unroll
  for (int i = 0; i < 8; ++i) {
    float* cp = C + (size_t)(bm + ty*8 + i) * N + bn + tx*8;
    *(float4*)cp     = make_float4(acc[i][0],acc[i][1],acc[i][2],acc[i][3]);
    *(float4*)(cp+4) = make_float4(acc[i][4],acc[i][5],acc[i][6],acc[i][7]);
  }
}

// ---------------------------------------------------------------------------
// Gate GEMM with fused gate_in construction:
//   A[row, col] = col<1024        ? hs[row,col]
//               : col<1280        ? mean_h short[row,*]
//               : col<1536        ? mean_h long_[row,*]
//               :                   mean_h delta[row,*]
// C = gelu(A @ W^T + bias).  M=LB, N=1024, K=1792.
// ---------------------------------------------------------------------------
__global__ __launch_bounds__(256)
void gemm_gate(const float* __restrict__ hs, const float* __restrict__ sh,
               const float* __restrict__ lo, const float* __restrict__ de,
               const float* __restrict__ W, const float* __restrict__ bias,
               float* __restrict__ C) {
  const int M = LB, N = GHC, K = GINC;
  __shared__ float As[16][128];
  __shared__ float Bs[16][128];
  const int tid = threadIdx.x;
  const int bn = blockIdx.x * 128;
  const int bm = blockIdx.y * 128;
  const int tx = tid & 15, ty = tid >> 4;
  const int lr = tid >> 1, lk = (tid & 1) * 8;

  float acc[8][8];
  #pragma unroll
  for (int i = 0; i < 8; ++i)
    #pragma unroll
    for (int j = 0; j < 8; ++j) acc[i][j] = 0.f;

  const size_t arow = (size_t)(bm + lr) * 1024;
  const float* Wp = W + (size_t)(bn + lr) * K + lk;

  for (int k0 = 0; k0 < K; k0 += 16) {
    const int col = k0 + lk;   // 8-aligned; the 8-col group never crosses a segment
    float4 a0, a1;
    if (col < 1024) {
      const float* p = hs + arow + col;
      a0 = *(const float4*)p; a1 = *(const float4*)(p + 4);
    } else {
      const int sec = (col - 1024) >> 8;
      const int d   = (col - 1024) & 255;
      const float* p = (sec == 0 ? sh : (sec == 1 ? lo : de)) + arow + d;
      float4 q0 = *(const float4*)(p);       float4 q1 = *(const float4*)(p+4);
      float4 r0 = *(const float4*)(p+256);   float4 r1 = *(const float4*)(p+260);
      float4 s0 = *(const float4*)(p+512);   float4 s1 = *(const float4*)(p+516);
      float4 t0 = *(const float4*)(p+768);   float4 t1 = *(const float4*)(p+772);
      a0 = make_float4(0.25f*(q0.x+r0.x+s0.x+t0.x), 0.25f*(q0.y+r0.y+s0.y+t0.y),
                       0.25f*(q0.z+r0.z+s0.z+t0.z), 0.25f*(q0.w+r0.w+s0.w+t0.w));
      a1 = make_float4(0.25f*(q1.x+r1.x+s1.x+t1.x), 0.25f*(q1.y+r1.y+s1.y+t1.y),
                       0.25f*(q1.z+r1.z+s1.z+t1.z), 0.25f*(q1.w+r1.w+s1.w+t1.w));
    }
    float4 b0 = *(const float4*)(Wp + k0);
    float4 b1 = *(const float4*)(Wp + k0 + 4);
    __syncthreads();
    As[lk+0][lr]=a0.x; As[lk+1][lr]=a0.y; As[lk+2][lr]=a0.z; As[lk+3][lr]=a0.w;
    As[lk+4][lr]=a1.x; As[lk+5][lr]=a1.y; As[lk+6][lr]=a1.z; As[lk+7][lr]=a1.w;
    Bs[lk+0][lr]=b0.x; Bs[lk+1][lr]=b0.y; Bs[lk+2][lr]=b0.z; Bs[lk+3][lr]=b0.w;
    Bs[lk+4][lr]=b1.x; Bs[lk+5][lr]=b1.y; Bs[lk+6][lr]=b1.z; Bs[lk+7][lr]=b1.w;
    __syncthreads();
    #pragma unroll
    for (int kk = 0; kk < 16; ++kk) {
      float av[8], bv[8];
      *(float4*)(av)   = *(const float4*)&As[kk][ty*8];
      *(float4*)(av+4) = *(const float4*)&As[kk][ty*8+4];
      *(float4*)(bv)   = *(const float4*)&Bs[kk][tx*8];
      *(float4*)(bv+4) = *(const float4*)&Bs[kk][tx*8+4];
      #pragma unroll
      for (int i = 0; i < 8; ++i)
        #pragma unroll
        for (int j = 0; j < 8; ++j) acc[i][j] += av[i]*bv[j];
    }
  }

  float bvals[8];
  #pragma unroll
  for (int j = 0; j < 8; ++j) bvals[j] = bias[bn + tx*8 + j];
  #pragma unroll
  for (int i = 0; i < 8; ++i) {
    float* cp = C + (size_t)(bm + ty*8 + i) * N + bn + tx*8;
    float out[8];
    #pragma unroll
    for (int j = 0; j < 8; ++j) {
      float v = acc[i][j] + bvals[j];
      out[j] = 0.5f * v * (1.0f + erff(v * 0.70710678118654752f));
    }
    *(float4*)cp     = make_float4(out[0],out[1],out[2],out[3]);
    *(float4*)(cp+4) = make_float4(out[4],out[5],out[6],out[7]);
  }
}

// ---------------------------------------------------------------------------
// Causal depthwise conv (k=4) + SiLU.  x,y: [LB, 1024], w: [1024,4]
// ---------------------------------------------------------------------------
__global__ __launch_bounds__(256)
void conv_silu_k(const float* __restrict__ x, const float* __restrict__ w,
                 float* __restrict__ y) {
  int idx = blockIdx.x * 256 + threadIdx.x;
  int c = idx & 1023;
  int l = idx >> 10;                 // row within this batch element
  float w0 = w[c*4+0], w1 = w[c*4+1], w2 = w[c*4+2], w3 = w[c*4+3];
  float acc = x[(size_t)l*1024 + c] * w3;
  if (l >= 1) acc += x[(size_t)(l-1)*1024 + c] * w2;
  if (l >= 2) acc += x[(size_t)(l-2)*1024 + c] * w1;
  if (l >= 3) acc += x[(size_t)(l-3)*1024 + c] * w0;
  y[idx] = acc / (1.f + expf(-acc));
}

// ---------------------------------------------------------------------------
// beta = sigmoid(hs @ b_proj_w^T)   one wave per row, 4 heads. [LB,4]
// ---------------------------------------------------------------------------
__global__ __launch_bounds__(256)
void beta_k(const float* __restrict__ hs, const float* __restrict__ bw,
            float* __restrict__ beta) {
  int row = blockIdx.x * 4 + (threadIdx.x >> 6);
  int ln  = threadIdx.x & 63;
  const float* xp = hs + (size_t)row * 1024 + ln*16;
  float a[4] = {0.f,0.f,0.f,0.f};
  #pragma unroll
  for (int t = 0; t < 4; ++t) {
    float4 xv = *(const float4*)(xp + t*4);
    #pragma unroll
    for (int h = 0; h < 4; ++h) {
      float4 wv = *(const float4*)(bw + (size_t)h*1024 + ln*16 + t*4);
      a[h] += dot4(xv, wv);
    }
  }
  #pragma unroll
  for (int h = 0; h < 4; ++h) {
    #pragma unroll
    for (int off = 32; off > 0; off >>= 1) a[h] += __shfl_xor(a[h], off, 64);
  }
  if (ln == 0) {
    #pragma unroll
    for (int h = 0; h < 4; ++h)
      beta[(size_t)row*4 + h] = 1.f / (1.f + expf(-a[h]));
  }
}

// ---------------------------------------------------------------------------
// Delta-rule phase A (per chunk, per head): l2-normalize q,k in place, build
// Tinv = (I + strict_lower(kb k^T))^-1, u = Tinv(v*beta), w = Tinv(k*beta),
// attn = tril(q k^T).    grid: 512 blocks (bid&3 = h, bid>>2 = chunk)
// ---------------------------------------------------------------------------
__global__ __launch_bounds__(256)
void delta_pre(float* __restrict__ q, float* __restrict__ k,
               const float* __restrict__ v, const float* __restrict__ beta,
               float* __restrict__ u, float* __restrict__ w,
               float* __restrict__ attn) {
  __shared__ float qs[32][260];
  __shared__ float ks[32][260];
  __shared__ float vs[32][260];
  __shared__ float Am[32][33];
  __shared__ float Ti[32][33];
  __shared__ float red[32][8];
  __shared__ float bet[32];

  const int bid = blockIdx.x;
  const int h  = bid & 3;
  const int c  = bid >> 2;
  const int tid = threadIdx.x;
  const int r  = tid >> 3;
  const int sg = tid & 7;

  const size_t base = (size_t)(c * CS) * 1024 + h * 256;
  float* qrow = q + base + (size_t)r * 1024 + sg * 32;
  float* krow = k + base + (size_t)r * 1024 + sg * 32;
  const float* vrow = v + base + (size_t)r * 1024 + sg * 32;

  #pragma unroll
  for (int t = 0; t < 8; ++t) {
    *(float4*)&qs[r][sg*32 + t*4] = *(const float4*)(qrow + t*4);
    *(float4*)&ks[r][sg*32 + t*4] = *(const float4*)(krow + t*4);
    *(float4*)&vs[r][sg*32 + t*4] = *(const float4*)(vrow + t*4);
  }
  if (tid < 32) bet[tid] = beta[(size_t)(c * CS + tid) * 4 + h];
  __syncthreads();

  // q normalization (and v *= beta)
  {
    float p = 0.f;
    #pragma unroll
    for (int i = 0; i < 32; ++i) { float x = qs[r][sg*32+i]; p += x*x; }
    red[r][sg] = p;
  }
  __syncthreads();
  {
    float s = 1e-12f;
    #pragma unroll
    for (int i = 0; i < 8; ++i) s += red[r][i];
    float qn = rsqrtf(s);
    #pragma unroll
    for (int t = 0; t < 8; ++t) {
      float4 vq = *(float4*)&qs[r][sg*32 + t*4];
      vq.x*=qn; vq.y*=qn; vq.z*=qn; vq.w*=qn;
      *(float4*)&qs[r][sg*32 + t*4] = vq;
      *(float4*)(qrow + t*4) = vq;
    }
    float bb = bet[r];
    #pragma unroll
    for (int t = 0; t < 8; ++t) {
      float4 vv = *(float4*)&vs[r][sg*32 + t*4];
      vv.x*=bb; vv.y*=bb; vv.z*=bb; vv.w*=bb;
      *(float4*)&vs[r][sg*32 + t*4] = vv;
    }
  }
  __syncthreads();
  // k normalization
  {
    float p = 0.f;
    #pragma unroll
    for (int i = 0; i < 32; ++i) { float x = ks[r][sg*32+i]; p += x*x; }
    red[r][sg] = p;
  }
  __syncthreads();
  {
    float s = 1e-12f;
    #pragma unroll
    for (int i = 0; i < 8; ++i) s += red[r][i];
    float kn = rsqrtf(s);
    #pragma unroll
    for (int t = 0; t < 8; ++t) {
      float4 vq = *(float4*)&ks[r][sg*32 + t*4];
      vq.x*=kn; vq.y*=kn; vq.z*=kn; vq.w*=kn;
      *(float4*)&ks[r][sg*32 + t*4] = vq;
      *(float4*)(krow + t*4) = vq;
    }
  }
  __syncthreads();

  // A = strict_lower(beta_r * k_r.k_s), attn = tril(q_r.k_s)
  {
    const int ti = tid >> 4, tj = tid & 15;
    const int r0 = ti*2, s0 = tj*2;
    float kk00=0,kk01=0,kk10=0,kk11=0,qk00=0,qk01=0,qk10=0,qk11=0;
    for (int d4 = 0; d4 < 64; ++d4) {
      float4 kr0 = *(const float4*)&ks[r0  ][d4*4];
      float4 kr1 = *(const float4*)&ks[r0+1][d4*4];
      float4 qr0 = *(const float4*)&qs[r0  ][d4*4];
      float4 qr1 = *(const float4*)&qs[r0+1][d4*4];
      float4 kc0 = *(const float4*)&ks[s0  ][d4*4];
      float4 kc1 = *(const float4*)&ks[s0+1][d4*4];
      kk00 += dot4(kr0,kc0); kk01 += dot4(kr0,kc1);
      kk10 += dot4(kr1,kc0); kk11 += dot4(kr1,kc1);
      qk00 += dot4(qr0,kc0); qk01 += dot4(qr0,kc1);
      qk10 += dot4(qr1,kc0); qk11 += dot4(qr1,kc1);
    }
    Am[r0  ][s0  ] = (r0   > s0  ) ? bet[r0  ]*kk00 : 0.f;
    Am[r0  ][s0+1] = (r0   > s0+1) ? bet[r0  ]*kk01 : 0.f;
    Am[r0+1][s0  ] = (r0+1 > s0  ) ? bet[r0+1]*kk10 : 0.f;
    Am[r0+1][s0+1] = (r0+1 > s0+1) ? bet[r0+1]*kk11 : 0.f;
    float* ap = attn + ((size_t)(h * NCH + c)) * 1024;
    ap[(r0  )*32 + s0  ] = (r0   >= s0  ) ? qk00 : 0.f;
    ap[(r0  )*32 + s0+1] = (r0   >= s0+1) ? qk01 : 0.f;
    ap[(r0+1)*32 + s0  ] = (r0+1 >= s0  ) ? qk10 : 0.f;
    ap[(r0+1)*32 + s0+1] = (r0+1 >= s0+1) ? qk11 : 0.f;
  }
  __syncthreads();

  // Tinv by forward substitution (one column per thread, unit diag)
  if (tid < 32) {
    const int cc = tid;
    Ti[cc][cc] = 1.f;
    for (int rr = cc+1; rr < 32; ++rr) {
      float s = Am[rr][cc];
      for (int ss = cc+1; ss < rr; ++ss) s += Am[rr][ss] * Ti[ss][cc];
      Ti[rr][cc] = -s;
    }
  }
  __syncthreads();

  // u = Tinv @ (v*beta)
  {
    float out[32];
    #pragma unroll
    for (int i = 0; i < 32; ++i) out[i] = vs[r][sg*32+i];
    for (int s2 = 0; s2 < r; ++s2) {
      float t = Ti[r][s2];
      #pragma unroll
      for (int t4 = 0; t4 < 8; ++t4) {
        float4 vv = *(const float4*)&vs[s2][sg*32 + t4*4];
        out[t4*4+0] += t*vv.x; out[t4*4+1] += t*vv.y;
        out[t4*4+2] += t*vv.z; out[t4*4+3] += t*vv.w;
      }
    }
    float* up = u + base + (size_t)r*1024 + sg*32;
    #pragma unroll
    for (int t4 = 0; t4 < 8; ++t4)
      *(float4*)(up + t4*4) = make_float4(out[t4*4],out[t4*4+1],out[t4*4+2],out[t4*4+3]);
  }
  // w = Tinv @ (k*beta)
  {
    float out[32];
    float br = bet[r];
    #pragma unroll
    for (int i = 0; i < 32; ++i) out[i] = br * ks[r][sg*32+i];
    for (int s2 = 0; s2 < r; ++s2) {
      float t = Ti[r][s2] * bet[s2];
      #pragma unroll
      for (int t4 = 0; t4 < 8; ++t4) {
        float4 vv = *(const float4*)&ks[s2][sg*32 + t4*4];
        out[t4*4+0] += t*vv.x; out[t4*4+1] += t*vv.y;
        out[t4*4+2] += t*vv.z; out[t4*4+3] += t*vv.w;
      }
    }
    float* wp = w + base + (size_t)r*1024 + sg*32;
    #pragma unroll
    for (int t4 = 0; t4 < 8; ++t4)
      *(float4*)(wp + t4*4) = make_float4(out[t4*4],out[t4*4+1],out[t4*4+2],out[t4*4+3]);
  }
}

// (r,oct) j-vectorized partial of  row[0:256] @ S[256][8]  (oct-blocked S)
__device__ __forceinline__ void smul8(const float* __restrict__ row,
                                      const float* __restrict__ Sb,
                                      float acc[8]) {
  #pragma unroll
  for (int i4 = 0; i4 < 8; ++i4) {
    float4 wq = *(const float4*)(row + i4*4);
    float wv[4] = {wq.x, wq.y, wq.z, wq.w};
    #pragma unroll
    for (int t = 0; t < 4; ++t) {
      const float* sp = Sb + (i4*4 + t)*8;
      float4 s0 = *(const float4*)sp;
      float4 s1 = *(const float4*)(sp + 4);
      acc[0] += wv[t]*s0.x; acc[1] += wv[t]*s0.y;
      acc[2] += wv[t]*s0.z; acc[3] += wv[t]*s0.w;
      acc[4] += wv[t]*s1.x; acc[5] += wv[t]*s1.y;
      acc[6] += wv[t]*s1.z; acc[7] += wv[t]*s1.w;
    }
  }
}

// ---------------------------------------------------------------------------
// Delta-rule phase B: sequential scan over 128 chunks.
// grid: 128 blocks, bid&3 = h, bid>>2 = dv group (8 cols).
// S[256][8] in LDS (oct-blocked), q/k/w staged per chunk.
// ---------------------------------------------------------------------------
__global__ __launch_bounds__(256)
void delta_scan(const float* __restrict__ q, const float* __restrict__ k,
                const float* __restrict__ w, const float* __restrict__ u,
                const float* __restrict__ attn, float* __restrict__ o) {
  __shared__ float ws_[32][260];
  __shared__ float qs[32][260];
  __shared__ float ks[32][260];
  __shared__ float Ssh[8*260];     // S[dk][j] at (dk>>5)*260 + (dk&31)*8 + j
  __shared__ float red[32][8][8];
  __shared__ float un[32][8];
  __shared__ float us[32][8];
  __shared__ float at[32][36];

  const int bid = blockIdx.x;
  const int h  = bid & 3;
  const int g  = bid >> 2;
  const int tid = threadIdx.x;
  const int r  = tid >> 3;
  const int sg = tid & 7;

  const size_t base = (size_t)h * 256;

  for (int i = tid; i < 8*260; i += 256) Ssh[i] = 0.f;

  for (int c = 0; c < NCH; ++c) {
    const size_t rowbase = base + (size_t)(c * CS) * 1024;
    // prefetch this chunk's operands into registers before the barrier
    const float* qp = q + rowbase + (size_t)r*1024 + sg*32;
    const float* kp = k + rowbase + (size_t)r*1024 + sg*32;
    const float* wp = w + rowbase + (size_t)r*1024 + sg*32;
    float4 qreg[8], kreg[8], wreg[8];
    #pragma unroll
    for (int t = 0; t < 8; ++t) {
      qreg[t] = *(const float4*)(qp + t*4);
      kreg[t] = *(const float4*)(kp + t*4);
      wreg[t] = *(const float4*)(wp + t*4);
    }
    float uval = u[rowbase + (size_t)r*1024 + g*8 + sg];
    float4 areg = *(const float4*)(attn + ((size_t)(h*NCH + c))*1024 + tid*4);

    __syncthreads();   // previous chunk fully done with staged LDS + S
    #pragma unroll
    for (int t = 0; t < 8; ++t) {
      *(float4*)&qs[r][sg*32 + t*4] = qreg[t];
      *(float4*)&ks[r][sg*32 + t*4] = kreg[t];
      *(float4*)&ws_[r][sg*32 + t*4] = wreg[t];
    }
    us[r][sg] = uval;
    at[r][sg*4+0] = areg.x; at[r][sg*4+1] = areg.y;
    at[r][sg*4+2] = areg.z; at[r][sg*4+3] = areg.w;
    __syncthreads();

    // M1 partial: (w @ S), thread = (r, oct=sg)
    {
      float acc[8];
      #pragma unroll
      for (int j = 0; j < 8; ++j) acc[j] = 0.f;
      smul8(&ws_[r][sg*32], &Ssh[sg*260], acc);
      *(float4*)&red[r][sg][0] = make_float4(acc[0],acc[1],acc[2],acc[3]);
      *(float4*)&red[r][sg][4] = make_float4(acc[4],acc[5],acc[6],acc[7]);
    }
    __syncthreads();
    // reduce: unew = u - w@S
    {
      float t = 0.f;
      #pragma unroll
      for (int o2 = 0; o2 < 8; ++o2) t += red[r][o2][sg];
      un[r][sg] = us[r][sg] - t;
    }
    __syncthreads();
    // M2 partial: q @ S + attn @ unew
    {
      float acc[8];
      #pragma unroll
      for (int j = 0; j < 8; ++j) acc[j] = 0.f;
      smul8(&qs[r][sg*32], &Ssh[sg*260], acc);
      #pragma unroll
      for (int t2 = 0; t2 < 4; ++t2) {
        int s2 = sg*4 + t2;
        float a = at[r][s2];
        float4 u0 = *(const float4*)&un[s2][0];
        float4 u1 = *(const float4*)&un[s2][4];
        acc[0] += a*u0.x; acc[1] += a*u0.y; acc[2] += a*u0.z; acc[3] += a*u0.w;
        acc[4] += a*u1.x; acc[5] += a*u1.y; acc[6] += a*u1.z; acc[7] += a*u1.w;
      }
      *(float4*)&red[r][sg][0] = make_float4(acc[0],acc[1],acc[2],acc[3]);
      *(float4*)&red[r][sg][4] = make_float4(acc[4],acc[5],acc[6],acc[7]);
    }
    __syncthreads();
    // o reduce+write, and M3: S += k^T @ unew (disjoint LDS regions)
    {
      float t = 0.f;
      #pragma unroll
      for (int o2 = 0; o2 < 8; ++o2) t += red[r][o2][sg];
      o[rowbase + (size_t)r*1024 + g*8 + sg] = t;
    }
    {
      const int dk = tid;
      float a2[8];
      #pragma unroll
      for (int j = 0; j < 8; ++j) a2[j] = 0.f;
      #pragma unroll 4
      for (int r2 = 0; r2 < 32; ++r2) {
        float kv = ks[r2][dk];
        float4 u0 = *(const float4*)&un[r2][0];
        float4 u1 = *(const float4*)&un[r2][4];
        a2[0] += kv*u0.x; a2[1] += kv*u0.y; a2[2] += kv*u0.z; a2[3] += kv*u0.w;
        a2[4] += kv*u1.x; a2[5] += kv*u1.y; a2[6] += kv*u1.z; a2[7] += kv*u1.w;
      }
      float* sp = &Ssh[(dk>>5)*260 + (dk&31)*8];
      float4 s0 = *(float4*)sp, s1 = *(float4*)(sp+4);
      s0.x += a2[0]; s0.y += a2[1]; s0.z += a2[2]; s0.w += a2[3];
      s1.x += a2[4]; s1.y += a2[5]; s1.z += a2[6]; s1.w += a2[7];
      *(float4*)sp = s0; *(float4*)(sp+4) = s1;
    }
  }
}

// ---------------------------------------------------------------------------
// Causal FIR depthwise conv, kernel size KF (3 or 31). x,y: [LB, 1024]
// ---------------------------------------------------------------------------
template<int KF>
__global__ __launch_bounds__(256)
void fir_k(const float* __restrict__ x, const float* __restrict__ wf,
           float* __restrict__ y) {
  int idx = blockIdx.x * 256 + threadIdx.x;
  int c = idx & 1023;
  int l = idx >> 10;
  const float* wp = wf + (size_t)c * KF;
  float acc = 0.f;
  #pragma unroll
  for (int j = 0; j < KF; ++j) {
    int ls = l - (KF-1) + j;
    if (ls >= 0) acc += x[(size_t)ls*1024 + c] * wp[j];
  }
  y[idx] = acc;
}

// ---------------------------------------------------------------------------
// logits -> softmax(T) -> floor/renorm weights.  One wave per row. [LB,4]
// ---------------------------------------------------------------------------
__global__ __launch_bounds__(256)
void logit_k(const float* __restrict__ hid, const float* __restrict__ w2,
             const float* __restrict__ b2, const float* __restrict__ lt,
             float* __restrict__ wgt) {
  int row = blockIdx.x * 4 + (threadIdx.x >> 6);
  int ln  = threadIdx.x & 63;
  const float* hp = hid + (size_t)row * 1024 + ln*16;
  float a[4] = {0.f,0.f,0.f,0.f};
  #pragma unroll
  for (int t = 0; t < 4; ++t) {
    float4 hv = *(const float4*)(hp + t*4);
    #pragma unroll
    for (int cc = 0; cc < 4; ++cc) {
      float4 wv = *(const float4*)(w2 + (size_t)cc*1024 + ln*16 + t*4);
      a[cc] += dot4(hv, wv);
    }
  }
  #pragma unroll
  for (int cc = 0; cc < 4; ++cc) {
    #pragma unroll
    for (int off = 32; off > 0; off >>= 1) a[cc] += __shfl_xor(a[cc], off, 64);
  }
  if (ln == 0) {
    float x = lt[0];
    float temp = (x > 20.f ? x : log1pf(expf(x))) + 1e-4f;
    float lg[4];
    #pragma unroll
    for (int cc = 0; cc < 4; ++cc) lg[cc] = (a[cc] + b2[cc]) / temp;
    float m = fmaxf(fmaxf(lg[0],lg[1]), fmaxf(lg[2],lg[3]));
    float e0 = expf(lg[0]-m), e1 = expf(lg[1]-m), e2 = expf(lg[2]-m), e3 = expf(lg[3]-m);
    float inv = 1.f / (e0+e1+e2+e3);
    float s0 = e0*inv, s1 = e1*inv, s2 = e2*inv, s3 = e3*inv;
    float fl = 0.05f * s3;
    float w0 = fmaxf(s0, fl), w1 = fmaxf(s1, fl);
    float tot = 1.f / (w0 + w1 + s2 + s3);
    float* wp = wgt + (size_t)row*4;
    wp[0] = w0*tot; wp[1] = w1*tot; wp[2] = s2*tot; wp[3] = s3*tot;
  }
}

// ---------------------------------------------------------------------------
// o = w0*short + w1*long + w2*delta + w3*v;  RMSNorm over DV; * o_norm_w
// one block per (l,h), 256 threads
// ---------------------------------------------------------------------------
__global__ __launch_bounds__(256)
void mix_k(const float* __restrict__ sh, const float* __restrict__ lo,
           const float* __restrict__ de, const float* __restrict__ v,
           const float* __restrict__ wgt, const float* __restrict__ onw,
           float* __restrict__ o) {
  int bid = blockIdx.x;
  int l = bid >> 2, h = bid & 3;
  int d = threadIdx.x;
  size_t off = (size_t)l*1024 + h*256 + d;
  const float* wp = wgt + (size_t)l*4;
  float w0 = wp[0], w1 = wp[1], w2 = wp[2], w3 = wp[3];
  float val = w0*sh[off] + w1*lo[off] + w2*de[off] + w3*v[off];
  __shared__ float rd[4];
  float ss = val*val;
  #pragma unroll
  for (int m = 32; m > 0; m >>= 1) ss += __shfl_xor(ss, m, 64);
  if ((threadIdx.x & 63) == 0) rd[threadIdx.x >> 6] = ss;
  __syncthreads();
  float tot = rd[0] + rd[1] + rd[2] + rd[3];
  float sc = rsqrtf(tot * (1.f/256.f) + 1e-5f);
  o[off] = val * sc * onw[d];
}

// ---------------------------------------------------------------------------
extern "C" void kernel_launch(void* const* d_in, const int* in_sizes, int n_in,
                              void* d_out, int out_size, void* d_ws, size_t ws_size,
                              hipStream_t stream) {
  (void)in_sizes; (void)n_in; (void)out_size; (void)ws_size;
  const float* hs   = (const float*)d_in[0];
  const float* qw   = (const float*)d_in[1];
  const float* kw   = (const float*)d_in[2];
  const float* vw   = (const float*)d_in[3];
  const float* bw   = (const float*)d_in[4];
  const float* qcw  = (const float*)d_in[5];
  const float* kcw  = (const float*)d_in[6];
  const float* vcw  = (const float*)d_in[7];
  const float* fsw  = (const float*)d_in[8];
  const float* flw  = (const float*)d_in[9];
  const float* fgw1 = (const float*)d_in[10];
  const float* fgb1 = (const float*)d_in[11];
  const float* fgw2 = (const float*)d_in[12];
  const float* fgb2 = (const float*)d_in[13];
  const float* ltmp = (const float*)d_in[14];
  const float* onw  = (const float*)d_in[15];
  const float* ow   = (const float*)d_in[16];

  // Per-batch-element workspace (processed b=0 then b=1): peak ~98 MB.
  float* ws0 = (float*)d_ws;
  const size_t SZB = (size_t)LB * 1024;          // 16 MB each
  float* A    = ws0;              // projection scratch, later delta output
  float* qb   = ws0 + SZB;        // q (post conv, then normalized), later FIR short
  float* kb2  = ws0 + 2*SZB;      // k, later FIR long
  float* vb   = ws0 + 3*SZB;      // v (post conv)
  float* ub   = ws0 + 4*SZB;      // u, later gate hidden
  float* wb   = ws0 + 5*SZB;      // w, later mix output
  float* att  = ws0 + 6*SZB;                    // [4,128,32,32] = 2 MB
  float* betab= att + (size_t)4*NCH*1024;       // [LB,4]
  float* wgtb = betab + (size_t)LB*4;           // [LB,4]

  dim3 blk(256);
  dim3 gg(1024/128, LB/128);       // square GEMMs, M=4096
  const int ELT = LB*1024/256;     // elementwise grid

  for (int b = 0; b < 2; ++b) {
    const float* hsb = hs + (size_t)b * LB * 1024;
    float* outb = (float*)d_out + (size_t)b * LB * 1024;

    gemm_bt<<<gg, blk, 0, stream>>>(hsb, qw, A, LB, 1024, 1024);
    conv_silu_k<<<dim3(ELT), blk, 0, stream>>>(A, qcw, qb);
    gemm_bt<<<gg, blk, 0, stream>>>(hsb, kw, A, LB, 1024, 1024);
    conv_silu_k<<<dim3(ELT), blk, 0, stream>>>(A, kcw, kb2);
    gemm_bt<<<gg, blk, 0, stream>>>(hsb, vw, A, LB, 1024, 1024);
    conv_silu_k<<<dim3(ELT), blk, 0, stream>>>(A, vcw, vb);

    beta_k<<<dim3(LB/4), blk, 0, stream>>>(hsb, bw, betab);
    delta_pre<<<dim3(512), blk, 0, stream>>>(qb, kb2, vb, betab, ub, wb, att);
    delta_scan<<<dim3(128), blk, 0, stream>>>(qb, kb2, wb, ub, att, A);

    fir_k<3><<<dim3(ELT), blk, 0, stream>>>(vb, fsw, qb);    // short -> qb
    fir_k<31><<<dim3(ELT), blk, 0, stream>>>(vb, flw, kb2);  // long  -> kb2

    gemm_gate<<<gg, blk, 0, stream>>>(hsb, qb, kb2, A, fgw1, fgb1, ub);
    logit_k<<<dim3(LB/4), blk, 0, stream>>>(ub, fgw2, fgb2, ltmp, wgtb);
    mix_k<<<dim3(LB*4), blk, 0, stream>>>(qb, kb2, A, vb, wgtb, onw, wb);

    gemm_bt<<<gg, blk, 0, stream>>>(wb, ow, outb, LB, 1024, 1024);
  }
}